// Round 5
// baseline (142.027 us; speedup 1.0000x reference)
//
#include <hip/hip_runtime.h>
#include <math.h>

// SGConv fully fused: one kernel. out[b,t,o] = bias[o] + sum_{dt,f} x[b,t+dt,f]*M[t][dt][f][o].
// sigma = ||lap||_2 reduced (tensor structure) to max over endpoint mu=-+2cos(pi/129)
// of lam_max(G_mu^T G_mu), 16x16 — computed WAVE-SYNCHRONOUSLY by wave 0 (no barriers;
// LDS ops within one wave are ordered), overlapped with waves 1-3 staging W and the
// first x chunk. M[80] built per-thread in registers (no global M round-trip, ws unused).
// R4 lesson: remaining cost was barrier cadence + 2nd launch + M global round-trip.

#define MU_MIN (-1.99940694f)   // -2*cos(pi/129)

__device__ __forceinline__ float dot16(float x) {  // sum over a 16-lane group
  x += __shfl_xor(x, 1);
  x += __shfl_xor(x, 2);
  x += __shfl_xor(x, 4);
  x += __shfl_xor(x, 8);
  return x;
}

__global__ __launch_bounds__(256) void k_fused(const float* __restrict__ adj,
                                               const float* __restrict__ W,
                                               const float* __restrict__ x,
                                               const float* __restrict__ bias,
                                               float* __restrict__ out) {
  const int bg = blockIdx.x;           // 0..31  -> 32 batches each
  const int tg = blockIdx.y;           // 0..7   -> 16 t each
  const int t0 = tg * 16, b0 = bg * 32;
  const int tid = threadIdx.x;

  __shared__ float Bsh[256], Wsh[768];
  __shared__ float dis_i[16], dis_b[16], csh[1], lamsh[2];
  __shared__ float H0[512], Pb[512], Qb[512];
  __shared__ float Dsh[18 * 256];      // D blocks for ta = t0-1 .. t0+16
  __shared__ float DDsh[16 * 256];     // D_t^2 for tl = 0..15
  __shared__ float xs[8 * 400];        // 8 batches x 20 rows x (16+4 pad)

  if (tid < 64) {
    // ---------------- wave 0: sigma, wave-synchronous (no block barriers) ----------------
    const int lane = tid;
    for (int e = lane; e < 256; e += 64) {
      const int f = e >> 4, g = e & 15;
      const float a = adj[e];
      const float s = 1.f / (1.f + expf(-a));
      Bsh[e] = (f == g) ? 1.f : s;     // B = feat + self-loop (asymmetric)
    }
    if (lane < 16) {
      float rs = 0.f;
      #pragma unroll
      for (int j = 0; j < 16; j++) rs += Bsh[lane * 16 + j];  // row sums (d = sum axis=1)
      dis_i[lane] = rsqrtf(rs + 2.f);  // interior t
      dis_b[lane] = rsqrtf(rs + 1.f);  // t in {0,127}
    }
    // G for both endpoint passes (pass = e>=256), into Pb
    for (int e = lane; e < 512; e += 64) {
      const int f = (e >> 4) & 15, g = e & 15;
      const float mu = (e & 256) ? -MU_MIN : MU_MIN;
      float gv = -dis_i[f] * Bsh[f * 16 + g] * dis_i[g];
      if (f == g) gv += 1.f - mu * dis_i[f] * dis_i[f];
      Pb[e] = gv;
    }
    // H = G^T G (symmetric PSD)
    for (int e = lane; e < 512; e += 64) {
      const int pb = e & ~255;
      const int r = (e >> 4) & 15, q = e & 15;
      float s = 0.f;
      #pragma unroll
      for (int k = 0; k < 16; k++) s += Pb[pb + k * 16 + r] * Pb[pb + k * 16 + q];
      H0[e] = s; Qb[e] = s;
    }
    float* cur = Qb;
    float* nxt = Pb;
    #pragma unroll 1
    for (int it = 0; it < 8; it++) {   // cur -> cur^2/tr^2  (H^256 total)
      float tr0 = 0.f, tr1 = 0.f;      // redundant per-lane trace reads (broadcast)
      #pragma unroll
      for (int d = 0; d < 16; d++) { tr0 += cur[d * 17]; tr1 += cur[256 + d * 17]; }
      const float s20 = 1.f / (tr0 * tr0), s21 = 1.f / (tr1 * tr1);
      for (int e = lane; e < 512; e += 64) {
        const int pb = e & ~255;
        const int r = (e >> 4) & 15, q = e & 15;
        const float4* rr = (const float4*)(cur + pb + r * 16);  // symmetric: col = row
        const float4* qq = (const float4*)(cur + pb + q * 16);
        float s = 0.f;
        #pragma unroll
        for (int k4 = 0; k4 < 4; k4++) {
          const float4 a = rr[k4], b = qq[k4];
          s += a.x * b.x + a.y * b.y + a.z * b.z + a.w * b.w;
        }
        nxt[e] = s * (pb ? s21 : s20);
      }
      float* tmp = cur; cur = nxt; nxt = tmp;
    }
    if (lane < 32) {                   // Rayleigh quotient, 16 lanes per pass
      const int pass = lane >> 4, pb = pass << 8, r = lane & 15;
      int bj = 0; float bd = -1.f;     // dominant column = argmax diag of H^256
      #pragma unroll
      for (int d = 0; d < 16; d++) {
        const float v = cur[pb + d * 17];
        if (v > bd) { bd = v; bj = d; }
      }
      const float vr = cur[pb + r * 16 + bj];
      float hv = 0.f;
      #pragma unroll
      for (int q = 0; q < 16; q++) hv += H0[pb + r * 16 + q] * cur[pb + q * 16 + bj];
      const float num = dot16(vr * hv);
      const float den = dot16(vr * vr);
      if (r == 0) lamsh[pass] = num / fmaxf(den, 1e-30f);
    }
    if (lane == 0) {
      const float lam = fmaxf(fmaxf(lamsh[0], lamsh[1]), 1e-20f);
      csh[0] = 2.f / sqrtf(lam);       // c = 2 / sigma
    }
  } else {
    // ---------------- waves 1-3: load W, pre-stage x chunk 0 ----------------
    const int id = tid - 64;
    for (int e = id; e < 768; e += 192) Wsh[e] = W[e];
    for (int idx = id; idx < 640; idx += 192) {
      const int cb = idx / 80, rem = idx % 80;
      const int rrow = rem >> 2, qq = rem & 3;
      int gr = t0 - 2 + rrow;
      gr = gr < 0 ? 0 : (gr > 127 ? 127 : gr);
      const float4 v = *(const float4*)(x + ((size_t)(b0 + cb) * 128 + gr) * 16 + qq * 4);
      *(float4*)(xs + cb * 400 + rrow * 20 + qq * 4) = v;
    }
  }
  __syncthreads();   // A: B, dis, csh, Wsh, xs chunk0 all visible

  const float c = csh[0];
  // ---------------- D blocks for ta = t0-1 .. t0+16 ----------------
  for (int e = tid; e < 18 * 256; e += 256) {
    const int tb = e >> 8, rq = e & 255;
    const int r = rq >> 4, q = rq & 15;
    int ta = t0 - 1 + tb;
    ta = ta < 0 ? 0 : (ta > 127 ? 127 : ta);   // clamped slots unused by guarded terms
    const float ur = (ta == 0 || ta == 127) ? dis_b[r] : dis_i[r];
    const float uq = (ta == 0 || ta == 127) ? dis_b[q] : dis_i[q];
    Dsh[e] = ((r == q) ? (c - 1.f) : 0.f) - c * ur * uq * Bsh[rq];
  }
  __syncthreads();   // B
  // ---------------- DD = D_t^2 for tl = 0..15 ----------------
  for (int e = tid; e < 16 * 256; e += 256) {
    const int tl = e >> 8, rq = e & 255;
    const int r = rq >> 4, q = rq & 15;
    const float* D0p = Dsh + (tl + 1) * 256;
    float s = 0.f;
    #pragma unroll
    for (int k = 0; k < 16; k++) s += D0p[r * 16 + k] * D0p[k * 16 + q];
    DDsh[e] = s;
  }
  __syncthreads();   // C

  // ---------------- per-thread M[80] in registers: thread (tl, o), t = t0+tl ----------------
  const int tl = tid >> 4, o = tid & 15;
  const int t = t0 + tl;
  float M[80];
  {
    const float* D0p = Dsh + (tl + 1) * 256;
    const float* Dmp = Dsh + tl * 256;
    const float* Dpp = Dsh + (tl + 2) * 256;
    const float* DDp = DDsh + tl * 256;
    float W1c[16], W2c[16];
    #pragma unroll
    for (int fp = 0; fp < 16; fp++) { W1c[fp] = Wsh[256 + fp * 16 + o]; W2c[fp] = Wsh[512 + fp * 16 + o]; }
    auto uat = [&](int a_, int ff) -> float {
      return (a_ == 0 || a_ == 127) ? dis_b[ff] : dis_i[ff];
    };
    #pragma unroll 1
    for (int fo = 0; fo < 16; fo++) {
      const float ut_f = uat(t, fo);
      // dt=0
      {
        float acc = Wsh[fo * 16 + o];
        const float diag0 = 2.f * c * c * ut_f * ut_f *
                            ((t > 0 ? uat(t - 1, fo) * uat(t - 1, fo) : 0.f) +
                             (t < 127 ? uat(t + 1, fo) * uat(t + 1, fo) : 0.f)) - 1.f;
        #pragma unroll
        for (int fp = 0; fp < 16; fp++) {
          acc += D0p[fo * 16 + fp] * W1c[fp];
          const float p2 = 2.f * DDp[fo * 16 + fp] + ((fo == fp) ? diag0 : 0.f);
          acc += p2 * W2c[fp];
        }
        M[2 * 16 + fo] = acc;
      }
      // dt=+1
      if (t < 127) {
        const float gf = -c * uat(t + 1, fo) * ut_f;
        float acc = gf * W1c[fo];
        #pragma unroll
        for (int fp = 0; fp < 16; fp++) {
          const float gq = -c * uat(t + 1, fp) * uat(t, fp);
          acc += 2.f * (gf * D0p[fo * 16 + fp] + Dpp[fo * 16 + fp] * gq) * W2c[fp];
        }
        M[3 * 16 + fo] = acc;
      } else M[3 * 16 + fo] = 0.f;
      // dt=-1
      if (t > 0) {
        const float gf = -c * uat(t - 1, fo) * ut_f;
        float acc = gf * W1c[fo];
        #pragma unroll
        for (int fp = 0; fp < 16; fp++) {
          const float gq = -c * uat(t - 1, fp) * uat(t, fp);
          acc += 2.f * (Dmp[fo * 16 + fp] * gq + gf * D0p[fo * 16 + fp]) * W2c[fp];
        }
        M[1 * 16 + fo] = acc;
      } else M[1 * 16 + fo] = 0.f;
      // dt=+/-2 (diagonal)
      M[4 * 16 + fo] = (t < 126) ? (2.f * c * c * uat(t + 2, fo) * uat(t + 1, fo) * uat(t + 1, fo)
                                    * ut_f * W2c[fo]) : 0.f;
      M[0 * 16 + fo] = (t > 1) ? (2.f * c * c * uat(t - 2, fo) * uat(t - 1, fo) * uat(t - 1, fo)
                                  * ut_f * W2c[fo]) : 0.f;
    }
  }
  const float bo = bias[o];

  // ---------------- conv: 4 chunks x 8 batches ----------------
  for (int cc = 0; cc < 4; cc++) {
    if (cc > 0) {
      __syncthreads();
      for (int idx = tid; idx < 640; idx += 256) {
        const int cb = idx / 80, rem = idx % 80;
        const int rrow = rem >> 2, qq = rem & 3;
        int gr = t0 - 2 + rrow;
        gr = gr < 0 ? 0 : (gr > 127 ? 127 : gr);
        const float4 v = *(const float4*)(x + ((size_t)(b0 + cc * 8 + cb) * 128 + gr) * 16 + qq * 4);
        *(float4*)(xs + cb * 400 + rrow * 20 + qq * 4) = v;
      }
      __syncthreads();
    }
    #pragma unroll
    for (int cb = 0; cb < 8; cb++) {
      float acc0 = bo, acc1 = 0.f;
      #pragma unroll
      for (int dt = 0; dt < 5; dt++) {
        const float* xr = xs + cb * 400 + (tl + dt) * 20;
        const float4 xa = *(const float4*)(xr);
        const float4 xb = *(const float4*)(xr + 4);
        const float4 xc = *(const float4*)(xr + 8);
        const float4 xd = *(const float4*)(xr + 12);
        const float* Mp = M + dt * 16;
        acc0 += xa.x * Mp[0] + xa.y * Mp[1] + xa.z * Mp[2] + xa.w * Mp[3]
              + xb.x * Mp[4] + xb.y * Mp[5] + xb.z * Mp[6] + xb.w * Mp[7];
        acc1 += xc.x * Mp[8] + xc.y * Mp[9] + xc.z * Mp[10] + xc.w * Mp[11]
              + xd.x * Mp[12] + xd.y * Mp[13] + xd.z * Mp[14] + xd.w * Mp[15];
      }
      out[((size_t)(b0 + cc * 8 + cb) * 128 + t) * 16 + o] = acc0 + acc1;
    }
  }
}

extern "C" void kernel_launch(void* const* d_in, const int* in_sizes, int n_in,
                              void* d_out, int out_size, void* d_ws, size_t ws_size,
                              hipStream_t stream) {
  const float* x    = (const float*)d_in[0];  // [1024,128,16]
  const float* W    = (const float*)d_in[1];  // [3,16,16]
  const float* bias = (const float*)d_in[2];  // [16]
  const float* adj  = (const float*)d_in[3];  // [16,16]
  float* out = (float*)d_out;
  (void)d_ws; (void)ws_size;                  // workspace no longer needed

  k_fused<<<dim3(32, 8), dim3(256), 0, stream>>>(adj, W, x, bias, out);
}

// Round 6
// 93.162 us; speedup vs baseline: 1.5245x; 1.5245x over previous
//
#include <hip/hip_runtime.h>
#include <math.h>

// SGConv: out[b,t,o] = bias[o] + sum_{dt,f} x[b,t+dt,f] * M[t][dt][f][o].
// Two kernels (R5 lesson: fusing forces 32x-redundant, bank-conflicted M-build):
//  kA (128 blocks, one per t): wave 0 computes sigma WAVE-SYNCHRONOUSLY
//     (no block barriers) while waves 1-3 load W; then R4's distributed
//     M-build (one (fo,o) pair per thread) -> ws.
//  k3 (512 blocks): banded conv, conflict-free LDS staging (verified R4 code).
// sigma = ||lap||_2 reduced via tensor structure to max over endpoint
// mu = -+2cos(pi/129) of lam_max(G_mu^T G_mu) (16x16), by 8 trace-normalized
// squarings (H^256) + one Rayleigh quotient.
//
// ws layout (floats): M[128][5][16][16] at 0 (163840 floats).

#define MU_MIN (-1.99940694f)   // -2*cos(pi/129)

__device__ __forceinline__ float dot16(float x) {  // sum over a 16-lane group
  x += __shfl_xor(x, 1);
  x += __shfl_xor(x, 2);
  x += __shfl_xor(x, 4);
  x += __shfl_xor(x, 8);
  return x;
}

// ---------------- Kernel A: sigma (wave-sync) + banded fused operator M ----------------
__global__ __launch_bounds__(256) void kA_build(const float* __restrict__ adj,
                                                const float* __restrict__ W,
                                                float* __restrict__ wsf) {
  const int t = blockIdx.x;
  const int tid = threadIdx.x;
  __shared__ float Bsh[256], Wsh[768];
  __shared__ float Dm[256], D0[256], Dp[256], DD[256];
  __shared__ float dis_i[16], dis_b[16], csh[1], lamsh[2];
  __shared__ float H0[512], Pb[512], Qb[512];

  if (tid < 64) {
    // -------- wave 0: sigma, wave-synchronous (LDS ops in-order within a wave) --------
    const int lane = tid;
    for (int e = lane; e < 256; e += 64) {
      const int f = e >> 4, g = e & 15;
      const float a = adj[e];
      const float s = 1.f / (1.f + expf(-a));
      Bsh[e] = (f == g) ? 1.f : s;     // B = feat + self-loop (asymmetric)
    }
    if (lane < 16) {
      float rs = 0.f;
      #pragma unroll
      for (int j = 0; j < 16; j++) rs += Bsh[lane * 16 + j];  // row sums (d = sum axis=1)
      dis_i[lane] = rsqrtf(rs + 2.f);  // interior t
      dis_b[lane] = rsqrtf(rs + 1.f);  // t in {0,127}
    }
    // G for both endpoint passes (pass bit = e&256), into Pb
    for (int e = lane; e < 512; e += 64) {
      const int f = (e >> 4) & 15, g = e & 15;
      const float mu = (e & 256) ? -MU_MIN : MU_MIN;
      float gv = -dis_i[f] * Bsh[f * 16 + g] * dis_i[g];
      if (f == g) gv += 1.f - mu * dis_i[f] * dis_i[f];
      Pb[e] = gv;
    }
    // H = G^T G (symmetric PSD)
    for (int e = lane; e < 512; e += 64) {
      const int pb = e & ~255;
      const int r = (e >> 4) & 15, q = e & 15;
      float s = 0.f;
      #pragma unroll
      for (int k = 0; k < 16; k++) s += Pb[pb + k * 16 + r] * Pb[pb + k * 16 + q];
      H0[e] = s; Qb[e] = s;
    }
    float* cur = Qb;
    float* nxt = Pb;
    #pragma unroll 1
    for (int it = 0; it < 8; it++) {   // cur -> cur^2/tr^2  (H^256 total)
      float tr0 = 0.f, tr1 = 0.f;      // redundant per-lane trace reads (broadcast)
      #pragma unroll
      for (int d = 0; d < 16; d++) { tr0 += cur[d * 17]; tr1 += cur[256 + d * 17]; }
      const float s20 = 1.f / (tr0 * tr0), s21 = 1.f / (tr1 * tr1);
      for (int e = lane; e < 512; e += 64) {
        const int pb = e & ~255;
        const int r = (e >> 4) & 15, q = e & 15;
        const float4* rr = (const float4*)(cur + pb + r * 16);  // symmetric: col = row
        const float4* qq = (const float4*)(cur + pb + q * 16);
        float s = 0.f;
        #pragma unroll
        for (int k4 = 0; k4 < 4; k4++) {
          const float4 a = rr[k4], b = qq[k4];
          s += a.x * b.x + a.y * b.y + a.z * b.z + a.w * b.w;
        }
        nxt[e] = s * (pb ? s21 : s20);
      }
      float* tmp = cur; cur = nxt; nxt = tmp;
    }
    if (lane < 32) {                   // Rayleigh quotient, 16 lanes per pass
      const int pass = lane >> 4, pb = pass << 8, r = lane & 15;
      int bj = 0; float bd = -1.f;     // dominant column = argmax diag of H^256
      #pragma unroll
      for (int d = 0; d < 16; d++) {
        const float v = cur[pb + d * 17];
        if (v > bd) { bd = v; bj = d; }
      }
      const float vr = cur[pb + r * 16 + bj];
      float hv = 0.f;
      #pragma unroll
      for (int q = 0; q < 16; q++) hv += H0[pb + r * 16 + q] * cur[pb + q * 16 + bj];
      const float num = dot16(vr * hv);
      const float den = dot16(vr * vr);
      if (r == 0) lamsh[pass] = num / fmaxf(den, 1e-30f);
    }
    if (lane == 0) {
      const float lam = fmaxf(fmaxf(lamsh[0], lamsh[1]), 1e-20f);
      csh[0] = 2.f / sqrtf(lam);       // c = 2 / sigma
    }
  } else {
    // -------- waves 1-3: load W --------
    const int id = tid - 64;
    for (int e = id; e < 768; e += 192) Wsh[e] = W[e];
  }
  __syncthreads();   // B, dis, csh, Wsh visible

  const float c = csh[0];
  const int r = tid >> 4, q = tid & 15;

  auto uat = [&](int a_, int ff) -> float {
    return (a_ == 0 || a_ == 127) ? dis_b[ff] : dis_i[ff];
  };

  // Ls diagonal blocks: D_a[f,f'] = (c-1) delta - c u_a(f) u_a(f') B[f,f']
  D0[tid] = ((r == q) ? (c - 1.f) : 0.f) - c * uat(t, r) * uat(t, q) * Bsh[tid];
  if (t > 0)   Dm[tid] = ((r == q) ? (c - 1.f) : 0.f) - c * uat(t - 1, r) * uat(t - 1, q) * Bsh[tid];
  if (t < 127) Dp[tid] = ((r == q) ? (c - 1.f) : 0.f) - c * uat(t + 1, r) * uat(t + 1, q) * Bsh[tid];
  __syncthreads();
  {
    float s = 0.f;
    #pragma unroll
    for (int k = 0; k < 16; k++) s += D0[r * 16 + k] * D0[k * 16 + q];
    DD[tid] = s;  // D_t^2
  }
  __syncthreads();

  const int fo = r;   // input feature f (row of P block at time t+dt)
  const int o = q;    // output channel
  float m[5];
  const float ut_f = uat(t, fo);

  // dt = 0:  W0 + D_t W1 + (2 D_t^2 + diag(2 c^2 u_t^2 (u_{t-1}^2 + u_{t+1}^2)) - I) W2
  {
    float acc = Wsh[fo * 16 + o];
    const float diag0 = 2.f * c * c * ut_f * ut_f *
                        ((t > 0 ? uat(t - 1, fo) * uat(t - 1, fo) : 0.f) +
                         (t < 127 ? uat(t + 1, fo) * uat(t + 1, fo) : 0.f)) - 1.f;
    #pragma unroll
    for (int fp = 0; fp < 16; fp++) {
      acc += D0[fo * 16 + fp] * Wsh[256 + fp * 16 + o];
      const float p2 = 2.f * DD[fo * 16 + fp] + ((fo == fp) ? diag0 : 0.f);
      acc += p2 * Wsh[512 + fp * 16 + o];
    }
    m[2] = acc;
  }
  // dt = +1: P1 = diag(g), P2 = 2(g(f) D_t + D_{t+1} g(f')),  g = -c u_{t+1} u_t
  if (t < 127) {
    const float gf = -c * uat(t + 1, fo) * ut_f;
    float acc = gf * Wsh[256 + fo * 16 + o];
    #pragma unroll
    for (int fp = 0; fp < 16; fp++) {
      const float gq = -c * uat(t + 1, fp) * uat(t, fp);
      const float p2 = 2.f * (gf * D0[fo * 16 + fp] + Dp[fo * 16 + fp] * gq);
      acc += p2 * Wsh[512 + fp * 16 + o];
    }
    m[3] = acc;
  } else m[3] = 0.f;
  // dt = -1
  if (t > 0) {
    const float gf = -c * uat(t - 1, fo) * ut_f;
    float acc = gf * Wsh[256 + fo * 16 + o];
    #pragma unroll
    for (int fp = 0; fp < 16; fp++) {
      const float gq = -c * uat(t - 1, fp) * uat(t, fp);
      const float p2 = 2.f * (Dm[fo * 16 + fp] * gq + gf * D0[fo * 16 + fp]);
      acc += p2 * Wsh[512 + fp * 16 + o];
    }
    m[1] = acc;
  } else m[1] = 0.f;
  // dt = +/-2: diagonal 2 c^2 u_{t+-2} u_{t+-1}^2 u_t
  m[4] = (t < 126) ? (2.f * c * c * uat(t + 2, fo) * uat(t + 1, fo) * uat(t + 1, fo) * ut_f
                      * Wsh[512 + fo * 16 + o]) : 0.f;
  m[0] = (t > 1) ? (2.f * c * c * uat(t - 2, fo) * uat(t - 1, fo) * uat(t - 1, fo) * ut_f
                    * Wsh[512 + fo * 16 + o]) : 0.f;

  #pragma unroll
  for (int d5 = 0; d5 < 5; d5++)
    wsf[((size_t)(t * 5 + d5) * 16 + fo) * 16 + o] = m[d5];
}

// ---------------- Kernel 3: out[b,t,o] = bias + sum_{dt,f} x[b,t+dt,f] M[t][dt][f][o] ----
__global__ __launch_bounds__(256) void k3_main(const float* __restrict__ x,
                                               const float* __restrict__ bias,
                                               const float* __restrict__ wsf,
                                               float* __restrict__ out) {
  const int tg = blockIdx.y, bg = blockIdx.x;
  const int t0 = tg * 16, b0 = bg * 16;
  const int tid = threadIdx.x;
  const int tl = tid >> 4, o = tid & 15;
  const int t = t0 + tl;

  float M[80];  // M column for this (t,o): [dt][f]
  {
    const float* Mt = wsf + (size_t)t * 5 * 256;
    #pragma unroll
    for (int i = 0; i < 80; i++) M[i] = Mt[i * 16 + o];
  }
  const float bo = bias[o];

  __shared__ float xs[1600];  // 4 batches x 20 rows x (16+4 pad) floats

  for (int cc = 0; cc < 4; cc++) {
    __syncthreads();
    for (int idx = tid; idx < 320; idx += 256) {
      const int cb = idx / 80, rem = idx % 80;
      const int rrow = rem >> 2, qq = rem & 3;
      int gr = t0 - 2 + rrow;
      gr = gr < 0 ? 0 : (gr > 127 ? 127 : gr);  // clamped rows hit M==0 entries
      const float4 v = *(const float4*)(x + ((size_t)(b0 + cc * 4 + cb) * 128 + gr) * 16 + qq * 4);
      *(float4*)(xs + cb * 400 + rrow * 20 + qq * 4) = v;
    }
    __syncthreads();
    #pragma unroll
    for (int cb = 0; cb < 4; cb++) {
      float acc0 = bo, acc1 = 0.f;
      #pragma unroll
      for (int dt = 0; dt < 5; dt++) {
        const float* xr = xs + cb * 400 + (tl + dt) * 20;
        const float4 xa = *(const float4*)(xr);
        const float4 xb = *(const float4*)(xr + 4);
        const float4 xc = *(const float4*)(xr + 8);
        const float4 xd = *(const float4*)(xr + 12);
        const float* Mp = M + dt * 16;
        acc0 += xa.x * Mp[0] + xa.y * Mp[1] + xa.z * Mp[2] + xa.w * Mp[3]
              + xb.x * Mp[4] + xb.y * Mp[5] + xb.z * Mp[6] + xb.w * Mp[7];
        acc1 += xc.x * Mp[8] + xc.y * Mp[9] + xc.z * Mp[10] + xc.w * Mp[11]
              + xd.x * Mp[12] + xd.y * Mp[13] + xd.z * Mp[14] + xd.w * Mp[15];
      }
      out[((size_t)(b0 + cc * 4 + cb) * 128 + t) * 16 + o] = acc0 + acc1;
    }
  }
}

extern "C" void kernel_launch(void* const* d_in, const int* in_sizes, int n_in,
                              void* d_out, int out_size, void* d_ws, size_t ws_size,
                              hipStream_t stream) {
  const float* x    = (const float*)d_in[0];  // [1024,128,16]
  const float* W    = (const float*)d_in[1];  // [3,16,16]
  const float* bias = (const float*)d_in[2];  // [16]
  const float* adj  = (const float*)d_in[3];  // [16,16]
  float* out = (float*)d_out;
  float* wsf = (float*)d_ws;  // needs 163840 floats (~656 KB)

  kA_build<<<dim3(128), dim3(256), 0, stream>>>(adj, W, wsf);
  k3_main<<<dim3(64, 8), dim3(256), 0, stream>>>(x, bias, wsf, out);
}

// Round 7
// 86.650 us; speedup vs baseline: 1.6391x; 1.0752x over previous
//
#include <hip/hip_runtime.h>
#include <math.h>

// SGConv: out[b,t,o] = bias[o] + sum_{dt,f} x[b,t+dt,f] * M[t][dt][f][o].
// THREE kernels (R6 lesson: recomputing sigma in all 128 kA blocks puts a
// ~10us latency chain in front of every M-build; R4/R6 A/B showed barrier-
// parallel sigma (12us) beats single-wave wave-sync sigma (20us) — barriers
// on a 4-wave block are cheap, serial LDS latency chains are not):
//  kS (1 block):    sigma via 8 trace-normalized squarings of H=G^T G for both
//                   endpoint mu (two 128-thread halves) + Rayleigh -> c into ws.
//  kM (128 blocks): banded fused operator M[t][dt][f][o] -> ws (R4 verified code).
//  k3 (512 blocks): banded conv, conflict-free LDS staging (R4 verified code).
// sigma = ||lap||_2 reduced via tensor structure: lap_u = sum_k s_k s_k^T (x) G_k,
// sigma_max(G_mu)^2 convex in mu => endpoints mu = -+2cos(pi/129) only.
//
// ws layout (floats): M[128][5][16][16] at 0 (163840 floats), c at 163840.

#define MU_MIN (-1.99940694f)   // -2*cos(pi/129)
#define C_OFF 163840

__device__ __forceinline__ float dot16(float x) {  // sum over a 16-lane group
  x += __shfl_xor(x, 1);
  x += __shfl_xor(x, 2);
  x += __shfl_xor(x, 4);
  x += __shfl_xor(x, 8);
  return x;
}

// ---------------- Kernel S: c = 2/sigma (single block, barrier-parallel) ----------------
__global__ __launch_bounds__(256) void kS_sigma(const float* __restrict__ adj,
                                                float* __restrict__ wsf) {
  const int tid = threadIdx.x;
  __shared__ float Bsh[256];
  __shared__ float dis_i[16];
  __shared__ float H0[512], Pb[512], Qb[512];
  __shared__ float scl[2], lamsh[2];
  __shared__ int jst[2];

  {
    const int f = tid >> 4, g = tid & 15;
    const float a = adj[tid];
    const float s = 1.f / (1.f + expf(-a));
    Bsh[tid] = (f == g) ? 1.f : s;     // B = feat + self-loop (asymmetric)
  }
  __syncthreads();
  if (tid < 16) {
    float rs = 0.f;
    #pragma unroll
    for (int j = 0; j < 16; j++) rs += Bsh[tid * 16 + j];  // row sums (d = sum axis=1)
    dis_i[tid] = rsqrtf(rs + 2.f);     // interior-degree u
  }
  __syncthreads();

  const int pass = tid >> 7, idx = tid & 127;
  const int pb = pass * 256;
  const float mu = pass ? -MU_MIN : MU_MIN;
  // G into Pb
  for (int e = idx; e < 256; e += 128) {
    const int f = e >> 4, g = e & 15;
    float gv = -dis_i[f] * Bsh[e] * dis_i[g];
    if (f == g) gv += 1.f - mu * dis_i[f] * dis_i[f];
    Pb[pb + e] = gv;
  }
  __syncthreads();
  // H0 = G^T G (symmetric PSD)
  for (int e = idx; e < 256; e += 128) {
    const int r = e >> 4, q = e & 15;
    float s = 0.f;
    #pragma unroll
    for (int k = 0; k < 16; k++) s += Pb[pb + k * 16 + r] * Pb[pb + k * 16 + q];
    H0[pb + e] = s;
    Qb[pb + e] = s;
  }
  __syncthreads();

  float* cur = Qb;
  float* nxt = Pb;
  #pragma unroll 1
  for (int it = 0; it < 8; it++) {   // cur -> cur^2 / tr^2   (H^256 total)
    if (idx == 0) {
      float tr = 0.f;
      #pragma unroll
      for (int d = 0; d < 16; d++) tr += cur[pb + d * 17];
      scl[pass] = 1.f / (tr * tr);
    }
    __syncthreads();
    const float s2 = scl[pass];
    for (int e = idx; e < 256; e += 128) {
      const int r = e >> 4, q = e & 15;
      const float4* rr = (const float4*)(cur + pb + r * 16);  // symmetric: col = row
      const float4* qq = (const float4*)(cur + pb + q * 16);
      float s = 0.f;
      #pragma unroll
      for (int k4 = 0; k4 < 4; k4++) {
        const float4 a = rr[k4], b = qq[k4];
        s += a.x * b.x + a.y * b.y + a.z * b.z + a.w * b.w;
      }
      nxt[pb + e] = s * s2;
    }
    __syncthreads();
    float* tmp = cur; cur = nxt; nxt = tmp;
  }
  if (idx == 0) {   // dominant column = argmax diagonal of H^256
    int bj = 0; float bd = -1.f;
    #pragma unroll
    for (int d = 0; d < 16; d++) {
      const float v = cur[pb + d * 17];
      if (v > bd) { bd = v; bj = d; }
    }
    jst[pass] = bj;
  }
  __syncthreads();
  if (idx < 16) {   // one-shot Rayleigh quotient of v = Hhat[:,j*] against H0
    const int r = idx, js = jst[pass];
    const float vr = cur[pb + r * 16 + js];
    float hv = 0.f;
    #pragma unroll
    for (int q = 0; q < 16; q++) hv += H0[pb + r * 16 + q] * cur[pb + q * 16 + js];
    const float num = dot16(vr * hv);
    const float den = dot16(vr * vr);
    if (r == 0) lamsh[pass] = num / fmaxf(den, 1e-30f);
  }
  __syncthreads();
  if (tid == 0) {
    const float lam = fmaxf(fmaxf(lamsh[0], lamsh[1]), 1e-20f);
    wsf[C_OFF] = 2.f / sqrtf(lam);   // c = 2 / sigma
  }
}

// ---------------- Kernel M: banded fused operator M[t][dt][f][o] ----------------
__global__ __launch_bounds__(256) void kM_build(const float* __restrict__ adj,
                                                const float* __restrict__ W,
                                                float* __restrict__ wsf) {
  const int t = blockIdx.x;
  const int tid = threadIdx.x;
  __shared__ float Bsh[256], Wsh[768];
  __shared__ float Dm[256], D0[256], Dp[256], DD[256];
  __shared__ float dis_i[16], dis_b[16], csh[1];

  {
    const int f = tid >> 4, g = tid & 15;
    const float a = adj[tid];
    const float s = 1.f / (1.f + expf(-a));
    Bsh[tid] = (f == g) ? 1.f : s;
    Wsh[tid] = W[tid];
    Wsh[tid + 256] = W[tid + 256];
    Wsh[tid + 512] = W[tid + 512];
    if (tid == 0) csh[0] = wsf[C_OFF];
  }
  __syncthreads();
  if (tid < 16) {
    float rs = 0.f;
    #pragma unroll
    for (int j = 0; j < 16; j++) rs += Bsh[tid * 16 + j];
    dis_i[tid] = rsqrtf(rs + 2.f);
    dis_b[tid] = rsqrtf(rs + 1.f);
  }
  __syncthreads();
  const float c = csh[0];
  const int r = tid >> 4, q = tid & 15;

  auto uat = [&](int a_, int ff) -> float {
    return (a_ == 0 || a_ == 127) ? dis_b[ff] : dis_i[ff];
  };

  // Ls diagonal blocks: D_a[f,f'] = (c-1) delta - c u_a(f) u_a(f') B[f,f']
  D0[tid] = ((r == q) ? (c - 1.f) : 0.f) - c * uat(t, r) * uat(t, q) * Bsh[tid];
  if (t > 0)   Dm[tid] = ((r == q) ? (c - 1.f) : 0.f) - c * uat(t - 1, r) * uat(t - 1, q) * Bsh[tid];
  if (t < 127) Dp[tid] = ((r == q) ? (c - 1.f) : 0.f) - c * uat(t + 1, r) * uat(t + 1, q) * Bsh[tid];
  __syncthreads();
  {
    float s = 0.f;
    #pragma unroll
    for (int k = 0; k < 16; k++) s += D0[r * 16 + k] * D0[k * 16 + q];
    DD[tid] = s;  // D_t^2
  }
  __syncthreads();

  const int fo = r;   // input feature f (row of P block at time t+dt)
  const int o = q;    // output channel
  float m[5];
  const float ut_f = uat(t, fo);

  // dt = 0:  W0 + D_t W1 + (2 D_t^2 + diag(2 c^2 u_t^2 (u_{t-1}^2 + u_{t+1}^2)) - I) W2
  {
    float acc = Wsh[fo * 16 + o];
    const float diag0 = 2.f * c * c * ut_f * ut_f *
                        ((t > 0 ? uat(t - 1, fo) * uat(t - 1, fo) : 0.f) +
                         (t < 127 ? uat(t + 1, fo) * uat(t + 1, fo) : 0.f)) - 1.f;
    #pragma unroll
    for (int fp = 0; fp < 16; fp++) {
      acc += D0[fo * 16 + fp] * Wsh[256 + fp * 16 + o];
      const float p2 = 2.f * DD[fo * 16 + fp] + ((fo == fp) ? diag0 : 0.f);
      acc += p2 * Wsh[512 + fp * 16 + o];
    }
    m[2] = acc;
  }
  // dt = +1: P1 = diag(g), P2 = 2(g(f) D_t + D_{t+1} g(f')),  g = -c u_{t+1} u_t
  if (t < 127) {
    const float gf = -c * uat(t + 1, fo) * ut_f;
    float acc = gf * Wsh[256 + fo * 16 + o];
    #pragma unroll
    for (int fp = 0; fp < 16; fp++) {
      const float gq = -c * uat(t + 1, fp) * uat(t, fp);
      const float p2 = 2.f * (gf * D0[fo * 16 + fp] + Dp[fo * 16 + fp] * gq);
      acc += p2 * Wsh[512 + fp * 16 + o];
    }
    m[3] = acc;
  } else m[3] = 0.f;
  // dt = -1
  if (t > 0) {
    const float gf = -c * uat(t - 1, fo) * ut_f;
    float acc = gf * Wsh[256 + fo * 16 + o];
    #pragma unroll
    for (int fp = 0; fp < 16; fp++) {
      const float gq = -c * uat(t - 1, fp) * uat(t, fp);
      const float p2 = 2.f * (Dm[fo * 16 + fp] * gq + gf * D0[fo * 16 + fp]);
      acc += p2 * Wsh[512 + fp * 16 + o];
    }
    m[1] = acc;
  } else m[1] = 0.f;
  // dt = +/-2: diagonal 2 c^2 u_{t+-2} u_{t+-1}^2 u_t
  m[4] = (t < 126) ? (2.f * c * c * uat(t + 2, fo) * uat(t + 1, fo) * uat(t + 1, fo) * ut_f
                      * Wsh[512 + fo * 16 + o]) : 0.f;
  m[0] = (t > 1) ? (2.f * c * c * uat(t - 2, fo) * uat(t - 1, fo) * uat(t - 1, fo) * ut_f
                    * Wsh[512 + fo * 16 + o]) : 0.f;

  #pragma unroll
  for (int d5 = 0; d5 < 5; d5++)
    wsf[((size_t)(t * 5 + d5) * 16 + fo) * 16 + o] = m[d5];
}

// ---------------- Kernel 3: out[b,t,o] = bias + sum_{dt,f} x[b,t+dt,f] M[t][dt][f][o] ----
__global__ __launch_bounds__(256) void k3_main(const float* __restrict__ x,
                                               const float* __restrict__ bias,
                                               const float* __restrict__ wsf,
                                               float* __restrict__ out) {
  const int tg = blockIdx.y, bg = blockIdx.x;
  const int t0 = tg * 16, b0 = bg * 16;
  const int tid = threadIdx.x;
  const int tl = tid >> 4, o = tid & 15;
  const int t = t0 + tl;

  float M[80];  // M column for this (t,o): [dt][f]
  {
    const float* Mt = wsf + (size_t)t * 5 * 256;
    #pragma unroll
    for (int i = 0; i < 80; i++) M[i] = Mt[i * 16 + o];
  }
  const float bo = bias[o];

  __shared__ float xs[1600];  // 4 batches x 20 rows x (16+4 pad) floats

  for (int cc = 0; cc < 4; cc++) {
    __syncthreads();
    for (int idx = tid; idx < 320; idx += 256) {
      const int cb = idx / 80, rem = idx % 80;
      const int rrow = rem >> 2, qq = rem & 3;
      int gr = t0 - 2 + rrow;
      gr = gr < 0 ? 0 : (gr > 127 ? 127 : gr);  // clamped rows hit M==0 entries
      const float4 v = *(const float4*)(x + ((size_t)(b0 + cc * 4 + cb) * 128 + gr) * 16 + qq * 4);
      *(float4*)(xs + cb * 400 + rrow * 20 + qq * 4) = v;
    }
    __syncthreads();
    #pragma unroll
    for (int cb = 0; cb < 4; cb++) {
      float acc0 = bo, acc1 = 0.f;
      #pragma unroll
      for (int dt = 0; dt < 5; dt++) {
        const float* xr = xs + cb * 400 + (tl + dt) * 20;
        const float4 xa = *(const float4*)(xr);
        const float4 xb = *(const float4*)(xr + 4);
        const float4 xc = *(const float4*)(xr + 8);
        const float4 xd = *(const float4*)(xr + 12);
        const float* Mp = M + dt * 16;
        acc0 += xa.x * Mp[0] + xa.y * Mp[1] + xa.z * Mp[2] + xa.w * Mp[3]
              + xb.x * Mp[4] + xb.y * Mp[5] + xb.z * Mp[6] + xb.w * Mp[7];
        acc1 += xc.x * Mp[8] + xc.y * Mp[9] + xc.z * Mp[10] + xc.w * Mp[11]
              + xd.x * Mp[12] + xd.y * Mp[13] + xd.z * Mp[14] + xd.w * Mp[15];
      }
      out[((size_t)(b0 + cc * 4 + cb) * 128 + t) * 16 + o] = acc0 + acc1;
    }
  }
}

extern "C" void kernel_launch(void* const* d_in, const int* in_sizes, int n_in,
                              void* d_out, int out_size, void* d_ws, size_t ws_size,
                              hipStream_t stream) {
  const float* x    = (const float*)d_in[0];  // [1024,128,16]
  const float* W    = (const float*)d_in[1];  // [3,16,16]
  const float* bias = (const float*)d_in[2];  // [16]
  const float* adj  = (const float*)d_in[3];  // [16,16]
  float* out = (float*)d_out;
  float* wsf = (float*)d_ws;  // needs 163841 floats (~656 KB)

  kS_sigma<<<dim3(1),   dim3(256), 0, stream>>>(adj, wsf);
  kM_build<<<dim3(128), dim3(256), 0, stream>>>(adj, W, wsf);
  k3_main<<<dim3(64, 8), dim3(256), 0, stream>>>(x, bias, wsf, out);
}